// Round 1
// 432.593 us; speedup vs baseline: 1.0599x; 1.0599x over previous
//
#include <hip/hip_runtime.h>
#include <math.h>

#define BB 32
#define FF 512
#define TT 4000
#define HH 8
#define NCH 8      // t-chunks
#define CHT 512    // t per chunk (last chunk = 416 = 13 tiles)
#define TILE 32    // t per tile

// ---------------------------------------------------------------------------
// prep_qk: qk[h*512+f] = (1/8) * sum_d q[h,d] * Wk[h*64+d, f]
//          qb[h]       = (1/8) * sum_d q[h,d] * bk[h*64+d]
// ---------------------------------------------------------------------------
__global__ __launch_bounds__(256) void prep_qk(const float* __restrict__ q,
                                               const float* __restrict__ Wk,
                                               const float* __restrict__ bk,
                                               float* __restrict__ qk,
                                               float* __restrict__ qb) {
    int gid = blockIdx.x * 256 + threadIdx.x;   // 0..4095
    int h = gid >> 9, f = gid & 511;
    float s = 0.f;
#pragma unroll 8
    for (int d = 0; d < 64; ++d)
        s += q[h * 64 + d] * Wk[(size_t)(h * 64 + d) * FF + f];
    qk[gid] = s * 0.125f;
    if (gid < HH) {
        float sb = 0.f;
        for (int d = 0; d < 64; ++d) sb += q[gid * 64 + d] * bk[gid * 64 + d];
        qb[gid] = sb * 0.125f;
    }
}

// ---------------------------------------------------------------------------
// prep_wvt: WvT[f*512+hv] = Wv[hv*512+f] via 64x64 LDS tile.
// ---------------------------------------------------------------------------
__global__ __launch_bounds__(256) void prep_wvt(const float* __restrict__ Wv,
                                                float* __restrict__ WvT) {
    __shared__ float tile[64][65];
    int hv0 = blockIdx.x * 64, f0 = blockIdx.y * 64;
    int tj = threadIdx.x & 63, ti = threadIdx.x >> 6;
#pragma unroll
    for (int r = 0; r < 16; ++r) {
        int i = ti * 16 + r;
        tile[i][tj] = Wv[(size_t)(hv0 + i) * FF + f0 + tj];
    }
    __syncthreads();
#pragma unroll
    for (int r = 0; r < 16; ++r) {
        int i = ti * 16 + r;
        WvT[(size_t)(f0 + i) * FF + hv0 + tj] = tile[tj][i];
    }
}

// ---------------------------------------------------------------------------
// k_fused: single pass over x. Per block: (b, t-chunk). 512 threads = 8 waves.
// Wave w == head h for score phase; thread f == tid for y-accumulate phase.
// LDS xs double-buffered, staged via global_load_lds (16B). XOR t-slot
// swizzle: slot s of row f holds data for true t4 = s ^ (f&7).
// Score-phase lane mapping: t4 = l&7, fs = l>>3  =>  each consecutive-8-lane
// ds_read_b128 phase reads one full contiguous 128B f-row (conflict-free).
// Per-tile: score (full-f dot from LDS, shuffle reduce) -> online softmax
// (m,l in wave-uniform regs) -> e to LDS -> y-accumulate w/ alpha rescale.
// Outputs per-chunk partials y_part/m_part/l_part.
// ---------------------------------------------------------------------------
#define XS_WORDS (2 * FF * TILE)          // 32768 floats, 128 KB
#define PS_OFF   XS_WORDS                 // ps[8][32]
#define AL_OFF   (PS_OFF + HH * TILE)     // al8[8]
#define QB_OFF   (AL_OFF + 8)             // qb8[8]
#define LDS_FLOATS (QB_OFF + 8)

extern __shared__ float smem[];

__global__ __launch_bounds__(512) void k_fused(
    const float* __restrict__ x, const int* __restrict__ wts,
    const float* __restrict__ qkg, const float* __restrict__ qbg,
    float* __restrict__ y_part, float* __restrict__ m_part,
    float* __restrict__ l_part) {
    float* xs  = smem;
    float* ps  = smem + PS_OFF;
    float* al8 = smem + AL_OFF;
    float* qb8 = smem + QB_OFF;

    const int b = blockIdx.y, ch = blockIdx.x;
    const int tid = threadIdx.x;
    const int w = tid >> 6;          // wave index == h
    const int l = tid & 63;
    const int t4 = l & 7;            // 0..7 : which 4-t group this lane scores
    const int fs = l >> 3;           // f-segment 0..7 (64 f each)
    const int f0 = fs * 64;
    const int h = w;
    const int tstart = ch * CHT;
    const int ntile = (ch == NCH - 1) ? 13 : 16;

    if (tid < 8) qb8[tid] = qbg[tid];

    // qk[h][f0..f0+63] resident in registers (16 float4)
    float4 qkr[16];
#pragma unroll
    for (int j4 = 0; j4 < 16; ++j4)
        qkr[j4] = *(const float4*)(qkg + h * FF + f0 + 4 * j4);

    float yacc[8];
#pragma unroll
    for (int i = 0; i < 8; ++i) yacc[i] = 0.f;
    float m_run = -3.0e38f, l_run = 0.f;

    const float* xb = x + (size_t)b * FF * TT;
    const int* wb = wts + (size_t)b * TT;

    // DMA stage: instrs [k0,k1) of tile kt into buffer bi.
    // u = k*512 + tid -> f = u>>3, slot t4s = u&7; global t4 = t4s ^ (f&7).
    // LDS dest is wave-uniform base + lane*16.
#define STAGE(kt, bi, k0, k1)                                                  \
    {                                                                          \
        int t0_ = tstart + (kt) * TILE;                                        \
        _Pragma("unroll")                                                      \
        for (int k = (k0); k < (k1); ++k) {                                    \
            int u = k * 512 + tid;                                             \
            int f_ = u >> 3, t4s = u & 7;                                      \
            int t4g = t4s ^ (f_ & 7);                                          \
            const float* g = xb + (size_t)f_ * TT + t0_ + 4 * t4g;             \
            float* ldst = xs + (bi) * (FF * TILE) + (k * 512 + w * 64) * 4;    \
            __builtin_amdgcn_global_load_lds(                                  \
                (const __attribute__((address_space(1))) unsigned int*)g,      \
                (__attribute__((address_space(3))) unsigned int*)ldst,         \
                16, 0, 0);                                                     \
        }                                                                      \
    }

    STAGE(0, 0, 0, 8);
    __syncthreads();   // drains DMA; qb8 visible

    const float qbh = qb8[h];   // hoisted: never rewritten after init

    for (int kt = 0; kt < ntile; ++kt) {
        int cur = kt & 1, nxt = cur ^ 1;
        // first half of next tile's stage: streams during score+accumulate
        if (kt + 1 < ntile) STAGE(kt + 1, nxt, 0, 4);

        // ---- score phase (reads cur) ----
        int tglob = tstart + kt * TILE + 4 * t4;
        int4 w4 = *(const int4*)(wb + tglob);          // mask, issued early
        const float* xcur = xs + cur * (FF * TILE);
        float4 s4 = make_float4(0.f, 0.f, 0.f, 0.f);
#pragma unroll
        for (int j4 = 0; j4 < 16; ++j4) {
            int f = f0 + 4 * j4;
            float4 qv = qkr[j4];
            float4 x0 = *(const float4*)(xcur + (f + 0) * TILE + 4 * (t4 ^ ((f + 0) & 7)));
            float4 x1 = *(const float4*)(xcur + (f + 1) * TILE + 4 * (t4 ^ ((f + 1) & 7)));
            float4 x2 = *(const float4*)(xcur + (f + 2) * TILE + 4 * (t4 ^ ((f + 2) & 7)));
            float4 x3 = *(const float4*)(xcur + (f + 3) * TILE + 4 * (t4 ^ ((f + 3) & 7)));
            s4.x += qv.x * x0.x + qv.y * x1.x + qv.z * x2.x + qv.w * x3.x;
            s4.y += qv.x * x0.y + qv.y * x1.y + qv.z * x2.y + qv.w * x3.y;
            s4.z += qv.x * x0.z + qv.y * x1.z + qv.z * x2.z + qv.w * x3.z;
            s4.w += qv.x * x0.w + qv.y * x1.w + qv.z * x2.w + qv.w * x3.w;
        }
        // reduce over f-segments (fs = l>>3 -> lanes xor 8,16,32)
#pragma unroll
        for (int mk = 8; mk <= 32; mk <<= 1) {
            s4.x += __shfl_xor(s4.x, mk);
            s4.y += __shfl_xor(s4.y, mk);
            s4.z += __shfl_xor(s4.z, mk);
            s4.w += __shfl_xor(s4.w, mk);
        }
        float sm0 = w4.x ? (s4.x + qbh) : -1e30f;
        float sm1 = w4.y ? (s4.y + qbh) : -1e30f;
        float sm2 = w4.z ? (s4.z + qbh) : -1e30f;
        float sm3 = w4.w ? (s4.w + qbh) : -1e30f;
        float tm = fmaxf(fmaxf(sm0, sm1), fmaxf(sm2, sm3));
#pragma unroll
        for (int mk = 1; mk <= 4; mk <<= 1) tm = fmaxf(tm, __shfl_xor(tm, mk));
        float nm = fmaxf(m_run, tm);
        float al = __expf(m_run - nm);
        float e0 = w4.x ? __expf(sm0 - nm) : 0.f;
        float e1 = w4.y ? __expf(sm1 - nm) : 0.f;
        float e2 = w4.z ? __expf(sm2 - nm) : 0.f;
        float e3 = w4.w ? __expf(sm3 - nm) : 0.f;
        float ts = e0 + e1 + e2 + e3;
#pragma unroll
        for (int mk = 1; mk <= 4; mk <<= 1) ts += __shfl_xor(ts, mk);
        l_run = al * l_run + ts;
        m_run = nm;
        if (fs == 0) *(float4*)(ps + h * TILE + 4 * t4) = make_float4(e0, e1, e2, e3);
        if (l == 0) al8[h] = al;

        // publish ps/al8 (LDS only) WITHOUT draining the in-flight DMA:
        // raw s_barrier preceded by lgkmcnt(0). DMA targets xs[nxt]; the
        // accumulate phase reads only xs[cur]/ps, so vmcnt may stay hot.
        asm volatile("s_waitcnt lgkmcnt(0)" ::: "memory");
        __builtin_amdgcn_s_barrier();
        __builtin_amdgcn_sched_barrier(0);

        // second half of next tile's stage: streams during accumulate
        if (kt + 1 < ntile) STAGE(kt + 1, nxt, 4, 8);

        // ---- accumulate phase: thread owns f = tid ----
#pragma unroll
        for (int hh = 0; hh < 8; ++hh) yacc[hh] *= al8[hh];
        const float* xrow = xcur + tid * TILE;
        int fx = tid & 7;
#pragma unroll
        for (int g = 0; g < 8; ++g) {
            float4 xv = *(const float4*)(xrow + 4 * (g ^ fx));
#pragma unroll
            for (int hh = 0; hh < 8; ++hh) {
                float4 e4 = *(const float4*)(ps + hh * TILE + 4 * g);
                yacc[hh] += e4.x * xv.x + e4.y * xv.y + e4.z * xv.z + e4.w * xv.w;
            }
        }
        __syncthreads();   // full drain: nxt fully staged; cur/ps reusable
    }

    // epilogue: per-chunk partials
#pragma unroll
    for (int hh = 0; hh < 8; ++hh)
        y_part[(((size_t)b * NCH + ch) * HH + hh) * FF + tid] = yacc[hh];
    if (l == 0) {
        m_part[(b * NCH + ch) * HH + h] = m_run;
        l_part[(b * NCH + ch) * HH + h] = l_run;
    }
}

// ---------------------------------------------------------------------------
// k_combine_out: merge chunk partials (flash-combine) then out = WvT . y + bv
// grid (2, 32); 256 threads.
// ---------------------------------------------------------------------------
__global__ __launch_bounds__(256) void k_combine_out(
    const float* __restrict__ y_part, const float* __restrict__ m_part,
    const float* __restrict__ l_part, const float* __restrict__ WvT,
    const float* __restrict__ bv, float* __restrict__ out) {
    __shared__ float ys[4][512];
    __shared__ float wj[4][NCH];
    __shared__ float invL[4], bsc[4];
    int half = blockIdx.x, b = blockIdx.y, tid = threadIdx.x;
    int h0 = half * 4;
    if (tid < 32) {
        int hl = tid >> 3, j = tid & 7;
        float m = m_part[(b * NCH + j) * HH + h0 + hl];
        float lv = l_part[(b * NCH + j) * HH + h0 + hl];
        float M = m;
#pragma unroll
        for (int mk = 1; mk <= 4; mk <<= 1) M = fmaxf(M, __shfl_xor(M, mk, 8));
        float a = __expf(m - M);
        float L = a * lv;
#pragma unroll
        for (int mk = 1; mk <= 4; mk <<= 1) L += __shfl_xor(L, mk, 8);
        wj[hl][j] = a;
        if (j == 0) {
            invL[hl] = (L > 0.f) ? 1.f / L : 0.f;
            bsc[hl] = (L > 0.f) ? 1.f : 0.f;
        }
    }
    __syncthreads();
    for (int i = tid; i < 2048; i += 256) {
        int hl = i >> 9, f = i & 511;
        float s = 0.f;
#pragma unroll
        for (int j = 0; j < NCH; ++j)
            s += wj[hl][j] * y_part[(((size_t)b * NCH + j) * HH + h0 + hl) * FF + f];
        ys[hl][f] = s * invL[hl];
    }
    __syncthreads();
    int hv = half * 256 + tid;
    int hloc = tid >> 6;
    const float* ysr = ys[hloc];
    float acc = 0.f;
#pragma unroll 8
    for (int f = 0; f < FF; ++f)
        acc += ysr[f] * WvT[(size_t)f * FF + hv];
    out[b * 512 + hv] = acc + bv[hv] * bsc[hloc];
}

// ---------------------------------------------------------------------------
// Workspace layout (floats):
//   qk 0 (4096) | qb 4096 (8) | WvT 8192 (262144)
//   y_part 270336 (32*8*8*512 = 1048576) | m_part 1318912 (2048)
//   l_part 1320960 (2048)
// ---------------------------------------------------------------------------
extern "C" void kernel_launch(void* const* d_in, const int* in_sizes, int n_in,
                              void* d_out, int out_size, void* d_ws, size_t ws_size,
                              hipStream_t stream) {
    const float* x   = (const float*)d_in[0];
    const int*   wts = (const int*)d_in[1];
    const float* q   = (const float*)d_in[2];
    const float* Wk  = (const float*)d_in[3];
    const float* bk  = (const float*)d_in[4];
    const float* Wv  = (const float*)d_in[5];
    const float* bv  = (const float*)d_in[6];
    float* out = (float*)d_out;
    float* ws  = (float*)d_ws;

    float* qk     = ws;
    float* qb     = ws + 4096;
    float* WvT    = ws + 8192;
    float* y_part = ws + 270336;
    float* m_part = ws + 1318912;
    float* l_part = ws + 1320960;

    prep_qk<<<16, 256, 0, stream>>>(q, Wk, bk, qk, qb);
    prep_wvt<<<dim3(8, 8), 256, 0, stream>>>(Wv, WvT);

    size_t lds_bytes = (size_t)LDS_FLOATS * 4;   // ~132 KB
    (void)hipFuncSetAttribute((const void*)k_fused,
                              hipFuncAttributeMaxDynamicSharedMemorySize,
                              (int)lds_bytes);
    k_fused<<<dim3(NCH, BB), 512, lds_bytes, stream>>>(
        x, wts, qk, qb, y_part, m_part, l_part);

    k_combine_out<<<dim3(2, BB), 256, 0, stream>>>(
        y_part, m_part, l_part, WvT, bv, out);
}